// Round 11
// baseline (676.329 us; speedup 1.0000x reference)
//
#include <hip/hip_runtime.h>

#define NN 20000
#define NE 640000
#define NBUK 79   // ceil(20000/256) buckets of 256 nodes
#define NPB 157   // partition blocks (ceil(E/4096))
#define CELL 128  // per (block,bucket) chunk capacity; P(overflow)~1e-17

// Self-probe: int64 edge data (values < 2^31) has every odd int32 word == 0.
__device__ __forceinline__ int probe_stride(const int* __restrict__ ei32) {
  int lane = threadIdx.x & 63;
  int v = ei32[2 * lane + 1];
  unsigned long long nz = __ballot(v != 0);
  return (nz == 0ull) ? 2 : 1;
}

__device__ __forceinline__ bool maskB(int var, int o2, int o1) {
  int s = o2 + o1;
  switch (var) {
    case 0: return (o2 >= 0) && (s >= 0);
    case 1: return s >= -1;
    case 3: return s <= 1;
    case 4: return (o2 <= 0) && (s <= 0);
    default: return true;
  }
}

// ============================ PHASE A1 =======================================
// blocks [0,151): weight setup (T729, beta5, Wt1, Wt2, Sbuf, c5)
// blocks [151,308): edge PARTITION into block-chunked ebuf2[block][bucket][128]
//   + private bhist row (R11: hist+partition fused; ei read once; no bases).
__global__ __launch_bounds__(256) void k_phaseA1(
    const int* __restrict__ ei, int* __restrict__ bhist,
    unsigned long long* __restrict__ ebuf2,
    const float* __restrict__ Wc1, const float* __restrict__ Wc2,
    const float* __restrict__ Wc3, const float* __restrict__ bc1,
    const float* __restrict__ bc2, const float* __restrict__ bc3,
    const float* __restrict__ Wl1, const float* __restrict__ Wr1,
    const float* __restrict__ Wl2, const float* __restrict__ Wr2,
    const float* __restrict__ bl2,
    float* __restrict__ T729, float* __restrict__ beta5,
    float* __restrict__ Wt1, float* __restrict__ Wt2,
    float* __restrict__ Sbuf, float* __restrict__ c5,
    int* __restrict__ rowptr, int E, int N) {
  __shared__ float smem[6336];  // max branch: T729 (576+5184+576)
  int b = blockIdx.x, tid = threadIdx.x;
  if (b >= 151) {
    // ---- partition (chunked, no global bases needed) ----
    int* lcnt = (int*)smem;
    int st = probe_stride(ei);
    for (int i = tid; i < NBUK; i += 256) lcnt[i] = 0;
    __syncthreads();
    int u = b - 151;
    int e0 = u * 4096;
    for (int t = 0; t < 16; ++t) {
      int e = e0 + t * 256 + tid;
      if (e < E) {
        int sv = ei[(size_t)e * st];
        int d  = ei[(size_t)(E + e) * st];
        int bb = d >> 8;
        int r = atomicAdd(&lcnt[bb], 1);
        ebuf2[((size_t)u * NBUK + bb) * CELL + r] =
            ((unsigned long long)(unsigned)d << 32) | (unsigned)sv;
      }
    }
    __syncthreads();
    for (int i = tid; i < NBUK; i += 256) bhist[u * NBUK + i] = lcnt[i];
    return;
  }
  int s = b;
  if (s == 0) {
    // ---- conv composite T729 ----
    float* W3  = smem;         // 576
    float* S9s = smem + 576;   // 5184
    float* W1s = smem + 5760;  // 576
    if (tid == 0) rowptr[N] = E;
    for (int e = tid; e < 576; e += 256) { W3[e] = Wc3[e]; W1s[e] = Wc1[e]; }
    __syncthreads();
    for (int bb = tid; bb < 576; bb += 256) {
      float acc[9];
#pragma unroll
      for (int a = 0; a < 9; ++a) acc[a] = 0.0f;
#pragma unroll 4
      for (int o = 0; o < 64; ++o) {
        float w2 = Wc2[o * 576 + bb];
#pragma unroll
        for (int a = 0; a < 9; ++a) acc[a] += W3[o * 9 + a] * w2;
      }
#pragma unroll
      for (int a = 0; a < 9; ++a) S9s[a * 576 + bb] = acc[a];
    }
    __syncthreads();
    for (int c = tid; c < 729; c += 256) {
      int kx0  = c % 3;
      int dl1e = (c / 3) % 3;
      int dl2e = (c / 9) % 3;
      int ky0  = (c / 27) % 3;
      int ky1  = (c / 81) % 3;
      int ky2  = c / 243;
      const float* s9 = &S9s[(ky2 * 3 + dl2e) * 576 + ky1 * 3 + dl1e];
      const float* w1 = &W1s[ky0 * 3 + kx0];
      float t = 0.0f;
#pragma unroll 8
      for (int i = 0; i < 64; ++i) t += s9[i * 9] * w1[i * 9];
      T729[c] = t;
    }
  } else if (s <= 5) {
    // ---- boundary beta vectors ----
    float* S2   = smem;          // 576
    float* W3b  = smem + 576;    // 576
    float* B2   = smem + 1152;   // 64
    float* part = smem + 1216;   // 256
    int var = s - 1;
    for (int e = tid; e < 576; e += 256) {
      int o = e / 9, r = e - o * 9;
      float t = 0.0f;
      for (int i = 0; i < 64; ++i) t += Wc2[o * 576 + i * 9 + r] * bc1[i];
      S2[e] = t;
      W3b[e] = Wc3[e];
    }
    if (tid < 64) B2[tid] = bc2[tid];
    __syncthreads();
    int u = tid & 63, oc = tid >> 6;
    float acc = 0.0f;
    for (int ky2 = 0; ky2 < 3; ++ky2) {
      int o2 = ky2 - 1;
      bool okA = (var == 0) ? (o2 >= 0) : (var == 4) ? (o2 <= 0) : true;
      if (!okA) continue;
      for (int dl2 = -1; dl2 <= 1; ++dl2) {
        int p = u + dl2; if ((unsigned)p >= 64u) continue;
        float sel[9];
#pragma unroll
        for (int ky1 = 0; ky1 < 3; ++ky1) {
          int o1 = ky1 - 1;
          bool mb = maskB(var, o2, o1);
#pragma unroll
          for (int dl1 = -1; dl1 <= 1; ++dl1) {
            int pq = p + dl1;
            sel[ky1 * 3 + dl1 + 1] = (mb && (unsigned)pq < 64u) ? 1.0f : 0.0f;
          }
        }
#pragma unroll 4
        for (int oo = 0; oo < 16; ++oo) {
          int o = oc * 16 + oo;
          float inner = B2[o];
#pragma unroll
          for (int r = 0; r < 9; ++r) inner += S2[o * 9 + r] * sel[r];
          acc += W3b[o * 9 + ky2 * 3 + (dl2 + 1)] * inner;
        }
      }
    }
    part[tid] = acc;
    __syncthreads();
    if (tid < 64) {
      beta5[var * 64 + tid] =
          bc3[0] + part[tid] + part[64 + tid] + part[128 + tid] + part[192 + tid];
    }
  } else {
    // ---- transposes + S-matrices + c5 ----
    int idx = (s - 6) * 256 + tid;  // 0..37119
    if (idx < 16384) {
      int w = idx >> 7, u = idx & 127;
      Wt1[idx] = (u < 64) ? Wl1[u * 128 + w] : Wr1[(u - 64) * 128 + w];
    } else if (idx < 24576) {
      int t = idx - 16384;
      int w = t >> 7, u = t & 127;
      Wt2[t] = (u < 64) ? Wl2[u * 64 + w] : Wr2[(u - 64) * 64 + w];
    } else if (idx < 36864) {
      // S2 = P·P, S1 = Q·P + P·Q, S0 = Q·Q  with P=Wl2^T, Q=Wr2^T.
      int t2 = idx - 24576;
      int m = t2 >> 12, e = t2 & 4095;
      int i = e >> 6, j = e & 63;
      float acc = 0.0f;
#pragma unroll 4
      for (int k = 0; k < 64; ++k) {
        float wlj = Wl2[j * 64 + k], wrj = Wr2[j * 64 + k];
        float wli = Wl2[k * 64 + i], wri = Wr2[k * 64 + i];
        if (m == 0) acc += wli * wlj;
        else if (m == 1) acc += wri * wlj + wli * wrj;
        else acc += wri * wrj;
      }
      Sbuf[t2] = acc;
    } else if (idx < 36928) {
      // c5 = bl2^T (P + Q + I)
      int j = idx - 36864;
      float acc = bl2[j];
      for (int i = 0; i < 64; ++i)
        acc += bl2[i] * (Wl2[j * 64 + i] + Wr2[j * 64 + i]);
      c5[j] = acc;
    }
  }
}

// ============================ PHASE A2 =======================================
// blocks [0,79): per-bucket counting sort over CHUNKED ebuf2 (offsets from
//   bhist; binary search per edge)
// blocks [79,141): M5T | block 141: Gbuf->Wg->bg->c32 chain | [142,1392): GEMM
__global__ __launch_bounds__(256) void k_phaseA2(
    const float* __restrict__ X, const float* __restrict__ Wt1,
    float* __restrict__ yzA,
    const unsigned long long* __restrict__ ebuf2,
    const int* __restrict__ bhist,
    int* __restrict__ rowptr, float* __restrict__ invdeg,
    int* __restrict__ csr,
    const float* __restrict__ T729, float* __restrict__ M5T,
    const float* __restrict__ Sbuf, const float* __restrict__ c5,
    const float* __restrict__ Wl3, const float* __restrict__ Wr3,
    const float* __restrict__ bl3, float* __restrict__ Gbuf,
    float* __restrict__ Wg, float* __restrict__ bg,
    const float* __restrict__ W2, const float* __restrict__ b2,
    float* __restrict__ c32, int E, int N) {
  __shared__ float smem[2048];  // max branch: gemm Xs (16x128) = 8KB
  int b = blockIdx.x, tid = threadIdx.x;
  if (b < NBUK) {
    // ---- sort bucket b from chunked cells ----
    int* lens  = (int*)smem;          // 160
    int* cs    = (int*)smem + 160;    // 256 (inclusive chunk-scan)
    int* lcnt  = (int*)smem + 416;    // 256
    int* lcur  = (int*)smem + 672;    // 256
    int* wsum  = (int*)smem + 928;    // 4
    int* sscan = (int*)smem + 932;    // 128
    int* tots  = (int*)smem + 1060;   // 128  (total 1188 ints)
    if (tid < 160) lens[tid] = (tid < NPB) ? bhist[tid * NBUK + b] : 0;
    int tot = 0;
    if (tid < NBUK)
      for (int v = 0; v < NPB; ++v) tot += bhist[v * NBUK + tid];
    if (tid < 128) {
      int tv = (tid < NBUK) ? tot : 0;
      tots[tid] = tv;
      sscan[tid] = tv;
    }
    __syncthreads();
    // inclusive scan of chunk lens over 256 (slots >=157 are 0-padded)
    {
      int mine = (tid < NPB) ? lens[tid] : 0;
      cs[tid] = mine;
      __syncthreads();
      for (int off = 1; off < 256; off <<= 1) {
        int v = (tid >= off) ? cs[tid - off] : 0;
        __syncthreads();
        cs[tid] += v;
        __syncthreads();
      }
    }
    // bucket-base scan (128-wide)
    for (int off = 1; off < 128; off <<= 1) {
      int v = 0;
      if (tid < 128 && tid >= off) v = sscan[tid - off];
      __syncthreads();
      if (tid < 128) sscan[tid] += v;
      __syncthreads();
    }
    if (tid < 128) sscan[tid] -= tots[tid];  // exclusive
    lcnt[tid] = 0;
    __syncthreads();
    int base = sscan[b];
    int n = cs[NPB - 1];
    // pass 1: count
    for (int i = tid; i < n; i += 256) {
      int lo = 0, hi = NPB - 1;
      while (lo < hi) { int mid = (lo + hi) >> 1; if (cs[mid] > i) hi = mid; else lo = mid + 1; }
      int pos = i - (cs[lo] - lens[lo]);
      unsigned long long pk = ebuf2[((size_t)lo * NBUK + b) * CELL + pos];
      atomicAdd(&lcnt[(int)(pk >> 32) & 255], 1);
    }
    __syncthreads();
    int c = lcnt[tid];
    int lane = tid & 63, wid = tid >> 6;
    int sacc = c;
#pragma unroll
    for (int off = 1; off < 64; off <<= 1) {
      int v = __shfl_up(sacc, off, 64);
      if (lane >= off) sacc += v;
    }
    if (lane == 63) wsum[wid] = sacc;
    __syncthreads();
    int woff = 0;
    for (int w = 0; w < wid; ++w) woff += wsum[w];
    int pref = woff + sacc - c;  // exclusive
    int gnode = (b << 8) + tid;
    if (gnode < N) {
      rowptr[gnode] = base + pref;
      invdeg[gnode] = 1.0f / (float)(c < 1 ? 1 : c);
    }
    lcur[tid] = pref;
    __syncthreads();
    // pass 2: place
    for (int i = tid; i < n; i += 256) {
      int lo = 0, hi = NPB - 1;
      while (lo < hi) { int mid = (lo + hi) >> 1; if (cs[mid] > i) hi = mid; else lo = mid + 1; }
      int pos = i - (cs[lo] - lens[lo]);
      unsigned long long pk = ebuf2[((size_t)lo * NBUK + b) * CELL + pos];
      int d = (int)(pk >> 32);
      int p2 = atomicAdd(&lcur[d & 255], 1);
      csr[base + p2] = (int)(unsigned)pk;
    }
  } else if (b < 141) {
    // ---- M5T ----
    float* Ts = smem;  // 729
    for (int e = tid; e < 729; e += 256) Ts[e] = T729[e];
    __syncthreads();
    int idx = (b - NBUK) * 256 + tid;
    if (idx >= 15680) return;
    int jw = idx % 7;
    int u  = (idx / 7) % 64;
    int d  = (idx / 448) % 7;
    int var = idx / 3136;
    int w = u + jw - 3;
    float acc = 0.0f;
    if (w >= 0 && w < 64) {
      for (int ky2 = 0; ky2 < 3; ++ky2) {
        int o2 = ky2 - 1;
        for (int ky1 = 0; ky1 < 3; ++ky1) {
          int o1 = ky1 - 1;
          if (!maskB(var, o2, o1)) continue;
          int o0 = (d - 3) - o2 - o1;
          if (o0 < -1 || o0 > 1) continue;
          int ky0 = o0 + 1;
          int cbase = ((ky2 * 3 + ky1) * 3 + ky0) * 27;
#pragma unroll
          for (int kx0 = 0; kx0 < 3; ++kx0) {
            int jq = jw - kx0;
            if ((unsigned)jq >= 5u) continue;
            int q = u + jq - 2;
            if ((unsigned)q >= 64u) continue;
#pragma unroll
            for (int dl2e = 0; dl2e < 3; ++dl2e) {
              int p = u + dl2e - 1;
              if ((unsigned)p >= 64u) continue;
              int dl1e = jq - dl2e;
              if ((unsigned)dl1e >= 3u) continue;
              acc += Ts[cbase + dl2e * 9 + dl1e * 3 + kx0];
            }
          }
        }
      }
    }
    if (d == 3 && jw == 3) acc += 1.0f;  // residual: out = conv(h) + h
    M5T[(var * 49 + d * 7 + jw) * 64 + u] = acc;
  } else if (b == 141) {
    // ---- chain: Gbuf -> (sync) -> Wg, bg, c32 ----
    // G3=S2·P3, G2=S1·P3+S2·Q3, G1=S0·P3+S1·Q3, G0=S0·Q3
    for (int idx = tid; idx < 8192; idx += 256) {
      int kblk = idx >> 11;
      int rem = idx & 2047;
      int t = rem >> 5, j = rem & 31;
      const float* S2p = Sbuf;
      const float* S1p = Sbuf + 4096;
      const float* S0p = Sbuf + 8192;
      const float* pa = (kblk == 0) ? S2p : (kblk == 1) ? S1p : (kblk == 2) ? S0p : nullptr;
      const float* pb = (kblk == 1) ? S2p : (kblk == 2) ? S1p : (kblk == 3) ? S0p : nullptr;
      float acc = 0.0f;
#pragma unroll 4
      for (int k = 0; k < 64; ++k) {
        if (pa) acc += pa[t * 64 + k] * Wl3[j * 64 + k];
        if (pb) acc += pb[t * 64 + k] * Wr3[j * 64 + k];
      }
      Gbuf[idx] = acc;
    }
    __syncthreads();  // vmcnt(0)+barrier: Gbuf visible to this block
    for (int idx = tid; idx < 8192; idx += 256) {
      int w = idx >> 7, u = idx & 127;
      int kblk = u >> 5, j = u & 31;
      const float* gp = Gbuf + kblk * 2048 + j;
      float acc = 0.0f;
#pragma unroll 4
      for (int t = 0; t < 64; ++t) acc += W2[t * 64 + w] * gp[t * 32];
      Wg[idx] = acc;
    }
    if (tid < 128) {
      int kblk = tid >> 5, j = tid & 31;
      const float* gp = Gbuf + kblk * 2048 + j;
      float acc = 0.0f;
      for (int t = 0; t < 64; ++t) acc += b2[t] * gp[t * 32];
      bg[tid] = acc;
    }
    if (tid < 32) {
      // c32 = c5^T (P3 + Q3) + bl3^T
      float acc = bl3[tid];
      for (int k = 0; k < 64; ++k)
        acc += c5[k] * (Wl3[tid * 64 + k] + Wr3[tid * 64 + k]);
      c32[tid] = acc;
    }
  } else {
    // ---- sage1 GEMM: yzA = x · Wt1  (C=128, K=128) ----
    constexpr int C = 128, K = 128, ROWS = 16, RPT = ROWS * C / 256;
    float* Xs = smem;
    int y0 = (b - 142) * ROWS;
    {
      const float4* src = (const float4*)(X + (size_t)y0 * K);
      float4* dst = (float4*)Xs;
#pragma unroll
      for (int v = 0; v < ROWS * K / 4 / 256; ++v)
        dst[v * 256 + tid] = src[v * 256 + tid];
    }
    __syncthreads();
    int u = tid % C;
    int rg = tid / C;
    float acc[RPT];
#pragma unroll
    for (int k = 0; k < RPT; ++k) acc[k] = 0.0f;
#pragma unroll 2
    for (int w0 = 0; w0 < K; w0 += 4) {
      float m0 = Wt1[(w0 + 0) * C + u];
      float m1 = Wt1[(w0 + 1) * C + u];
      float m2 = Wt1[(w0 + 2) * C + u];
      float m3 = Wt1[(w0 + 3) * C + u];
      const float* xs = &Xs[(rg * RPT) * K + w0];
#pragma unroll
      for (int k = 0; k < RPT; ++k) {
        float4 h = *(const float4*)(xs + k * K);
        acc[k] += m0 * h.x + m1 * h.y + m2 * h.z + m3 * h.w;
      }
    }
#pragma unroll
    for (int k = 0; k < RPT; ++k)
      yzA[(size_t)(y0 + rg * RPT + k) * C + u] = acc[k];
  }
}

// ------------------- fused mean-aggregation + GEMM --------------------------
// (R8 fp32 body verbatim — best-measured variant)
template <int C>
__global__ __launch_bounds__(256) void k_fused(const float* __restrict__ yzin,
                                               const int* __restrict__ csr,
                                               const int* __restrict__ rowptr,
                                               const float* __restrict__ invdeg,
                                               const float* __restrict__ bl,
                                               const float* __restrict__ Wt,
                                               float* __restrict__ out, int N) {
  constexpr int FV = 16;
  constexpr int G  = 4;
  constexpr int S4 = 32;
  constexpr int CAP = 64;
  __shared__ int idxs[16 * CAP];
  __shared__ float htile[16 * 64];
  int tid = threadIdx.x;
  int w = tid >> 6, lane = tid & 63;
  int base = blockIdx.x * 16;
  int beg_r[4], m_r[4], end_r[4];
#pragma unroll
  for (int rr = 0; rr < 4; ++rr) {
    int node = base + w * 4 + rr;
    int beg = rowptr[node], end = rowptr[node + 1];
    beg_r[rr] = beg; end_r[rr] = end;
    int cnt = end - beg;
    int m = cnt < CAP ? cnt : CAP;
    m_r[rr] = m;
    int* my = &idxs[(w * 4 + rr) * CAP];
    for (int k = lane; k < m; k += 64) my[k] = csr[beg + k];
  }
  __syncthreads();
  int g = lane / FV, f = lane % FV;
  const float4* yz4 = (const float4*)yzin;
#pragma unroll
  for (int rr = 0; rr < 4; ++rr) {
    int node = base + w * 4 + rr;
    const int* my = &idxs[(w * 4 + rr) * CAP];
    int m = m_r[rr];
    float a0x=0,a0y=0,a0z=0,a0w=0, a1x=0,a1y=0,a1z=0,a1w=0;
    float a2x=0,a2y=0,a2z=0,a2w=0, a3x=0,a3y=0,a3z=0,a3w=0;
    int j = g;
    for (; j + 3 * G < m; j += 4 * G) {
      int s0 = my[j], s1 = my[j + G], s2 = my[j + 2 * G], s3 = my[j + 3 * G];
      float4 v0 = yz4[(size_t)s0 * S4 + f];
      float4 v1 = yz4[(size_t)s1 * S4 + f];
      float4 v2 = yz4[(size_t)s2 * S4 + f];
      float4 v3 = yz4[(size_t)s3 * S4 + f];
      a0x += v0.x; a0y += v0.y; a0z += v0.z; a0w += v0.w;
      a1x += v1.x; a1y += v1.y; a1z += v1.z; a1w += v1.w;
      a2x += v2.x; a2y += v2.y; a2z += v2.z; a2w += v2.w;
      a3x += v3.x; a3y += v3.y; a3z += v3.z; a3w += v3.w;
    }
    for (; j < m; j += G) {
      int s0 = my[j];
      float4 v0 = yz4[(size_t)s0 * S4 + f];
      a0x += v0.x; a0y += v0.y; a0z += v0.z; a0w += v0.w;
    }
    for (int jj = beg_r[rr] + CAP + g; jj < end_r[rr]; jj += G) {
      int s0 = csr[jj];
      float4 v0 = yz4[(size_t)s0 * S4 + f];
      a0x += v0.x; a0y += v0.y; a0z += v0.z; a0w += v0.w;
    }
    float ax = (a0x + a1x) + (a2x + a3x);
    float ay = (a0y + a1y) + (a2y + a3y);
    float az = (a0z + a1z) + (a2z + a3z);
    float aw = (a0w + a1w) + (a2w + a3w);
#pragma unroll
    for (int mm = FV; mm < 64; mm <<= 1) {
      ax += __shfl_xor(ax, mm, 64);
      ay += __shfl_xor(ay, mm, 64);
      az += __shfl_xor(az, mm, 64);
      aw += __shfl_xor(aw, mm, 64);
    }
    if (g == 0) {
      float4 root = yz4[(size_t)node * S4 + FV + f];
      float4 bv = ((const float4*)bl)[f];
      float id = invdeg[node];
      float4 o;
      o.x = ax * id + bv.x + root.x;
      o.y = ay * id + bv.y + root.y;
      o.z = az * id + bv.z + root.z;
      o.w = aw * id + bv.w + root.w;
      ((float4*)htile)[(w * 4 + rr) * 16 + f] = o;
    }
  }
  __syncthreads();
  constexpr int RPT = 16 * C / 256;
  int u = tid % C, rg = tid / C;
  float acc[RPT];
#pragma unroll
  for (int k = 0; k < RPT; ++k) acc[k] = 0.0f;
#pragma unroll 2
  for (int w0 = 0; w0 < 64; w0 += 4) {
    float m0 = Wt[(w0 + 0) * C + u];
    float m1 = Wt[(w0 + 1) * C + u];
    float m2 = Wt[(w0 + 2) * C + u];
    float m3 = Wt[(w0 + 3) * C + u];
    const float* xs = &htile[(rg * RPT) * 64 + w0];
#pragma unroll
    for (int k = 0; k < RPT; ++k) {
      float4 h4 = *(const float4*)(xs + k * 64);
      acc[k] += m0 * h4.x + m1 * h4.y + m2 * h4.z + m3 * h4.w;
    }
  }
#pragma unroll
  for (int k = 0; k < RPT; ++k)
    out[(size_t)(base + rg * RPT + k) * C + u] = acc[k];
}

// ---------- fused conv-composite apply + (linear2 ∘ sage4-6 collapse) -------
__global__ __launch_bounds__(256) void k_applyfused(
    const float* __restrict__ h, const float* __restrict__ M5T,
    const float* __restrict__ beta5, const float* __restrict__ Wg,
    const float* __restrict__ bg, float* __restrict__ wout, int N) {
  __shared__ float hs[22 * 70];
  __shared__ float htile[16 * 64];
  int tid = threadIdx.x;
  int bstart = blockIdx.x * 16;
  for (int idx = tid; idx < 22 * 70; idx += 256) {
    int row = idx / 70, col = idx - row * 70;
    int y = bstart - 3 + row;
    int ww = col - 3;
    float v = 0.0f;
    if ((unsigned)y < (unsigned)N && (unsigned)ww < 64u)
      v = h[(size_t)y * 64 + ww];
    hs[idx] = v;
  }
  __syncthreads();
  int u = tid & 63, g = tid >> 6;
  int lr0 = g * 4;
  int gstart = bstart + lr0;
  const float* basep = &hs[lr0 * 70 + u];
  bool interior = (gstart >= 2) && (gstart + 3 <= N - 3);
  if (interior) {
    float c[49];
#pragma unroll
    for (int t = 0; t < 49; ++t) c[t] = M5T[(2 * 49 + t) * 64 + u];
    float bet = beta5[2 * 64 + u];
    float acc[4];
#pragma unroll
    for (int k = 0; k < 4; ++k) acc[k] = bet;
#pragma unroll
    for (int rr = 0; rr < 10; ++rr) {
      float t7[7];
#pragma unroll
      for (int jw = 0; jw < 7; ++jw) t7[jw] = basep[rr * 70 + jw];
#pragma unroll
      for (int d = 0; d < 7; ++d) {
        int k = rr - d;
        if (k >= 0 && k < 4) {
#pragma unroll
          for (int jw = 0; jw < 7; ++jw) acc[k] += c[d * 7 + jw] * t7[jw];
        }
      }
    }
#pragma unroll
    for (int k = 0; k < 4; ++k) htile[(lr0 + k) * 64 + u] = acc[k];
  } else {
    for (int k = 0; k < 4; ++k) {
      int y = gstart + k;
      int var = (y == 0) ? 0 : (y == 1) ? 1 : (y == N - 2) ? 3 : (y == N - 1) ? 4 : 2;
      float acc = beta5[var * 64 + u];
      for (int d = 0; d < 7; ++d)
        for (int jw = 0; jw < 7; ++jw)
          acc += M5T[(var * 49 + d * 7 + jw) * 64 + u] * basep[(k + d) * 70 + jw];
      htile[(lr0 + k) * 64 + u] = acc;
    }
  }
  __syncthreads();
  int u2 = tid % 128, rg = tid / 128;
  float acc2[8];
  float bv = bg[u2];
#pragma unroll
  for (int k = 0; k < 8; ++k) acc2[k] = bv;
#pragma unroll 2
  for (int w0 = 0; w0 < 64; w0 += 4) {
    float m0 = Wg[(w0 + 0) * 128 + u2];
    float m1 = Wg[(w0 + 1) * 128 + u2];
    float m2 = Wg[(w0 + 2) * 128 + u2];
    float m3 = Wg[(w0 + 3) * 128 + u2];
    const float* xs = &htile[(rg * 8) * 64 + w0];
#pragma unroll
    for (int k = 0; k < 8; ++k) {
      float4 h4 = *(const float4*)(xs + k * 64);
      acc2[k] += m0 * h4.x + m1 * h4.y + m2 * h4.z + m3 * h4.w;
    }
  }
  int kb = u2 >> 5, jj = u2 & 31;
#pragma unroll
  for (int k = 0; k < 8; ++k) {
    int node = bstart + rg * 8 + k;
    wout[((size_t)kb * N + node) * 32 + jj] = acc2[k];
  }
}

// ------------------ standalone mean aggregation (agg3) ----------------------
template <int DH>
__global__ __launch_bounds__(256) void k_agg(const float* __restrict__ yz,
                                             const int* __restrict__ csr,
                                             const int* __restrict__ rowptr,
                                             const float* __restrict__ invdeg,
                                             const float* __restrict__ bl,
                                             float* __restrict__ out, int N) {
  constexpr int FV = DH / 4;
  constexpr int G  = 64 / FV;
  constexpr int S4 = DH / 2;
  constexpr int CAP = 256;
  __shared__ int idxs[4 * CAP];
  int wid = threadIdx.x >> 6, lane = threadIdx.x & 63;
  int node = blockIdx.x * 4 + wid;
  int beg = rowptr[node], end = rowptr[node + 1];
  int cnt = end - beg;
  int m = cnt < CAP ? cnt : CAP;
  int* my = &idxs[wid * CAP];
  for (int k = lane; k < m; k += 64) my[k] = csr[beg + k];
  __syncthreads();
  int g = lane / FV, f = lane % FV;
  const float4* yz4 = (const float4*)yz;
  float a0x=0,a0y=0,a0z=0,a0w=0, a1x=0,a1y=0,a1z=0,a1w=0;
  float a2x=0,a2y=0,a2z=0,a2w=0, a3x=0,a3y=0,a3z=0,a3w=0;
  int j = g;
  for (; j + 3 * G < m; j += 4 * G) {
    int s0 = my[j], s1 = my[j + G], s2 = my[j + 2 * G], s3 = my[j + 3 * G];
    float4 v0 = yz4[(size_t)s0 * S4 + f];
    float4 v1 = yz4[(size_t)s1 * S4 + f];
    float4 v2 = yz4[(size_t)s2 * S4 + f];
    float4 v3 = yz4[(size_t)s3 * S4 + f];
    a0x += v0.x; a0y += v0.y; a0z += v0.z; a0w += v0.w;
    a1x += v1.x; a1y += v1.y; a1z += v1.z; a1w += v1.w;
    a2x += v2.x; a2y += v2.y; a2z += v2.z; a2w += v2.w;
    a3x += v3.x; a3y += v3.y; a3z += v3.z; a3w += v3.w;
  }
  for (; j < m; j += G) {
    int s0 = my[j];
    float4 v0 = yz4[(size_t)s0 * S4 + f];
    a0x += v0.x; a0y += v0.y; a0z += v0.z; a0w += v0.w;
  }
  for (int jj = beg + CAP + g; jj < end; jj += G) {
    int s0 = csr[jj];
    float4 v0 = yz4[(size_t)s0 * S4 + f];
    a0x += v0.x; a0y += v0.y; a0z += v0.z; a0w += v0.w;
  }
  float ax = (a0x + a1x) + (a2x + a3x);
  float ay = (a0y + a1y) + (a2y + a3y);
  float az = (a0z + a1z) + (a2z + a3z);
  float aw = (a0w + a1w) + (a2w + a3w);
#pragma unroll
  for (int mm = FV; mm < 64; mm <<= 1) {
    ax += __shfl_xor(ax, mm, 64);
    ay += __shfl_xor(ay, mm, 64);
    az += __shfl_xor(az, mm, 64);
    aw += __shfl_xor(aw, mm, 64);
  }
  if (g == 0) {
    float4 root = yz4[(size_t)node * S4 + FV + f];
    float4 bv = ((const float4*)bl)[f];
    float id = invdeg[node];
    float4 o;
    o.x = ax * id + bv.x + root.x;
    o.y = ay * id + bv.y + root.y;
    o.z = az * id + bv.z + root.z;
    o.w = aw * id + bv.w + root.w;
    ((float4*)out)[(size_t)node * FV + f] = o;
  }
}

// ---- 32-wide mean aggregation + elementwise add: out = (A src)·invdeg + add [+ cvec]
__global__ __launch_bounds__(256) void k_agg32(
    const float* __restrict__ src, const int* __restrict__ csr,
    const int* __restrict__ rowptr, const float* __restrict__ invdeg,
    const float* __restrict__ add, const float* __restrict__ cvec,
    float* __restrict__ out, int N) {
  constexpr int FV = 8;    // float4 per 32-float row
  constexpr int G  = 8;    // neighbor-parallel groups per wave
  constexpr int CAP = 256;
  __shared__ int idxs[4 * CAP];
  int wid = threadIdx.x >> 6, lane = threadIdx.x & 63;
  int node = blockIdx.x * 4 + wid;
  int beg = rowptr[node], end = rowptr[node + 1];
  int cnt = end - beg;
  int m = cnt < CAP ? cnt : CAP;
  int* my = &idxs[wid * CAP];
  for (int k = lane; k < m; k += 64) my[k] = csr[beg + k];
  __syncthreads();
  int g = lane / FV, f = lane % FV;
  const float4* sr4 = (const float4*)src;
  float a0x=0,a0y=0,a0z=0,a0w=0, a1x=0,a1y=0,a1z=0,a1w=0;
  float a2x=0,a2y=0,a2z=0,a2w=0, a3x=0,a3y=0,a3z=0,a3w=0;
  int j = g;
  for (; j + 3 * G < m; j += 4 * G) {
    int s0 = my[j], s1 = my[j + G], s2 = my[j + 2 * G], s3 = my[j + 3 * G];
    float4 v0 = sr4[(size_t)s0 * FV + f];
    float4 v1 = sr4[(size_t)s1 * FV + f];
    float4 v2 = sr4[(size_t)s2 * FV + f];
    float4 v3 = sr4[(size_t)s3 * FV + f];
    a0x += v0.x; a0y += v0.y; a0z += v0.z; a0w += v0.w;
    a1x += v1.x; a1y += v1.y; a1z += v1.z; a1w += v1.w;
    a2x += v2.x; a2y += v2.y; a2z += v2.z; a2w += v2.w;
    a3x += v3.x; a3y += v3.y; a3z += v3.z; a3w += v3.w;
  }
  for (; j < m; j += G) {
    int s0 = my[j];
    float4 v0 = sr4[(size_t)s0 * FV + f];
    a0x += v0.x; a0y += v0.y; a0z += v0.z; a0w += v0.w;
  }
  for (int jj = beg + CAP + g; jj < end; jj += G) {
    int s0 = csr[jj];
    float4 v0 = sr4[(size_t)s0 * FV + f];
    a0x += v0.x; a0y += v0.y; a0z += v0.z; a0w += v0.w;
  }
  float ax = (a0x + a1x) + (a2x + a3x);
  float ay = (a0y + a1y) + (a2y + a3y);
  float az = (a0z + a1z) + (a2z + a3z);
  float aw = (a0w + a1w) + (a2w + a3w);
#pragma unroll
  for (int mm = FV; mm < 64; mm <<= 1) {
    ax += __shfl_xor(ax, mm, 64);
    ay += __shfl_xor(ay, mm, 64);
    az += __shfl_xor(az, mm, 64);
    aw += __shfl_xor(aw, mm, 64);
  }
  if (g == 0) {
    float4 av = ((const float4*)add)[(size_t)node * FV + f];
    float id = invdeg[node];
    float4 o;
    o.x = ax * id + av.x;
    o.y = ay * id + av.y;
    o.z = az * id + av.z;
    o.w = aw * id + av.w;
    if (cvec != nullptr) {
      float4 cv = ((const float4*)cvec)[f];
      o.x += cv.x; o.y += cv.y; o.z += cv.z; o.w += cv.w;
    }
    ((float4*)out)[(size_t)node * FV + f] = o;
  }
}

// ------------------------------- launcher -----------------------------------
extern "C" void kernel_launch(void* const* d_in, const int* in_sizes, int n_in,
                              void* d_out, int out_size, void* d_ws, size_t ws_size,
                              hipStream_t stream) {
  const int N = NN, E = NE;
  const float* x   = (const float*)d_in[0];
  const int*   ei  = (const int*)d_in[1];
  const float* Wl1 = (const float*)d_in[2];
  const float* bl1 = (const float*)d_in[3];
  const float* Wr1 = (const float*)d_in[4];
  const float* Wl2 = (const float*)d_in[5];
  const float* bl2 = (const float*)d_in[6];
  const float* Wr2 = (const float*)d_in[7];
  const float* Wl3 = (const float*)d_in[8];
  const float* bl3 = (const float*)d_in[9];
  const float* Wr3 = (const float*)d_in[10];
  const float* Wc1 = (const float*)d_in[11];
  const float* bc1 = (const float*)d_in[12];
  const float* Wc2 = (const float*)d_in[13];
  const float* bc2 = (const float*)d_in[14];
  const float* Wc3 = (const float*)d_in[15];
  const float* bc3 = (const float*)d_in[16];
  const float* W2  = (const float*)d_in[17];
  const float* b2  = (const float*)d_in[18];

  char* ws = (char*)d_ws;
  size_t off = 0;
  auto alloc = [&](size_t bytes) -> void* {
    off = (off + 255) & ~(size_t)255;
    void* p = ws + off;
    off += bytes;
    return p;
  };
  int*   rowptr  = (int*)alloc((size_t)(N + 1) * 4);
  float* invdeg  = (float*)alloc((size_t)N * 4);
  int*   csr     = (int*)alloc((size_t)E * 4);
  unsigned long long* ebuf2 =
      (unsigned long long*)alloc((size_t)NPB * NBUK * CELL * 8);  // 12.7 MB
  int*   bhist   = (int*)alloc(NPB * NBUK * 4);  // per-block hist rows
  float* Wt1     = (float*)alloc(128 * 128 * 4);
  float* Wt2     = (float*)alloc(64 * 128 * 4);
  float* T729    = (float*)alloc(729 * 4);
  float* M5T     = (float*)alloc(15680 * 4);
  float* beta5   = (float*)alloc(320 * 4);
  float* Sbuf    = (float*)alloc(12288 * 4);
  float* c5      = (float*)alloc(64 * 4);
  float* Gbuf    = (float*)alloc(8192 * 4);
  float* Wg      = (float*)alloc(8192 * 4);
  float* bg      = (float*)alloc(128 * 4);
  float* c32     = (float*)alloc(32 * 4);
  float* yzA     = (float*)alloc((size_t)N * 128 * 4);
  float* yzB     = (float*)alloc((size_t)N * 128 * 4);
  float* hA      = (float*)alloc((size_t)N * 64 * 4);
  float* wbuf    = (float*)alloc((size_t)4 * N * 32 * 4);
  float* s1buf   = (float*)alloc((size_t)N * 32 * 4);
  float* s2buf   = (float*)alloc((size_t)N * 32 * 4);
  (void)ws_size; (void)in_sizes; (void)n_in; (void)out_size;

  const int gG = N / 16;  // 1250
  const int gA = N / 4;   // 5000

  // A1: setup(151) || chunked-partition(157)
  k_phaseA1<<<308, 256, 0, stream>>>(ei, bhist, ebuf2,
                                     Wc1, Wc2, Wc3, bc1, bc2, bc3,
                                     Wl1, Wr1, Wl2, Wr2, bl2,
                                     T729, beta5, Wt1, Wt2, Sbuf, c5,
                                     rowptr, E, N);
  // A2: sort(79) || m5(62) || GW-chain(1) || sage1-GEMM(1250)
  k_phaseA2<<<1392, 256, 0, stream>>>(x, Wt1, yzA, ebuf2, bhist,
                                      rowptr, invdeg, csr,
                                      T729, M5T, Sbuf, c5, Wl3, Wr3, bl3,
                                      Gbuf, Wg, bg, W2, b2, c32, E, N);

  // [agg1 + sage2-transform]
  k_fused<128><<<gG, 256, 0, stream>>>(yzA, csr, rowptr, invdeg, bl1, Wt2, yzB, N);
  // [agg2 + sage3-transform]
  k_fused<128><<<gG, 256, 0, stream>>>(yzB, csr, rowptr, invdeg, bl2, Wt2, yzA, N);
  // agg3 -> hA (conv input)
  k_agg<64><<<gA, 256, 0, stream>>>(yzA, csr, rowptr, invdeg, bl2, hA, N);
  // [conv-composite + residual + linear2 + sage4-6 weight collapse]
  k_applyfused<<<gG, 256, 0, stream>>>(hA, M5T, beta5, Wg, bg, wbuf, N);
  // collapsed sage4-6: out = A(A(A w3 + w2) + w1) + w0 + c32
  const float* w3  = wbuf;
  const float* w2p = wbuf + (size_t)N * 32;
  const float* w1p = wbuf + (size_t)2 * N * 32;
  const float* w0p = wbuf + (size_t)3 * N * 32;
  k_agg32<<<gA, 256, 0, stream>>>(w3, csr, rowptr, invdeg, w2p, nullptr, s1buf, N);
  k_agg32<<<gA, 256, 0, stream>>>(s1buf, csr, rowptr, invdeg, w1p, nullptr, s2buf, N);
  k_agg32<<<gA, 256, 0, stream>>>(s2buf, csr, rowptr, invdeg, w0p, c32, (float*)d_out, N);
}

// Round 13
// 279.950 us; speedup vs baseline: 2.4159x; 2.4159x over previous
//
#include <hip/hip_runtime.h>

#define NN 20000
#define NE 640000
#define NBUK 79  // ceil(20000/256) buckets of 256 nodes

// Self-probe: int64 edge data (values < 2^31) has every odd int32 word == 0.
__device__ __forceinline__ int probe_stride(const int* __restrict__ ei32) {
  int lane = threadIdx.x & 63;
  int v = ei32[2 * lane + 1];
  unsigned long long nz = __ballot(v != 0);
  return (nz == 0ull) ? 2 : 1;
}

__device__ __forceinline__ bool maskB(int var, int o2, int o1) {
  int s = o2 + o1;
  switch (var) {
    case 0: return (o2 >= 0) && (s >= 0);
    case 1: return s >= -1;
    case 3: return s <= 1;
    case 4: return (o2 <= 0) && (s <= 0);
    default: return true;
  }
}

// ============================ PHASE A1 =======================================
// blocks [0,151): weight setup (T729, beta5, Wt1, Wt2, Sbuf, c5)
// blocks [151,308): edge histogram -> PRIVATE rows bhist[u][79] (plain stores,
//   no zero-init, no atomics).
__global__ __launch_bounds__(256) void k_phaseA1(
    const int* __restrict__ ei, int* __restrict__ bhist,
    const float* __restrict__ Wc1, const float* __restrict__ Wc2,
    const float* __restrict__ Wc3, const float* __restrict__ bc1,
    const float* __restrict__ bc2, const float* __restrict__ bc3,
    const float* __restrict__ Wl1, const float* __restrict__ Wr1,
    const float* __restrict__ Wl2, const float* __restrict__ Wr2,
    const float* __restrict__ bl2,
    float* __restrict__ T729, float* __restrict__ beta5,
    float* __restrict__ Wt1, float* __restrict__ Wt2,
    float* __restrict__ Sbuf, float* __restrict__ c5,
    int* __restrict__ rowptr, int E, int N) {
  __shared__ float smem[6336];  // max branch: T729 (576+5184+576)
  int b = blockIdx.x, tid = threadIdx.x;
  if (b >= 151) {
    // ---- histogram (private row, no global atomics) ----
    int* lb = (int*)smem;
    int st = probe_stride(ei);
    for (int i = tid; i < NBUK; i += 256) lb[i] = 0;
    __syncthreads();
    int u = b - 151;
    int e0 = u * 4096;
#pragma unroll
    for (int t = 0; t < 16; ++t) {
      int e = e0 + t * 256 + tid;
      if (e < E) atomicAdd(&lb[ei[(size_t)(E + e) * st] >> 8], 1);
    }
    __syncthreads();
    for (int i = tid; i < NBUK; i += 256) bhist[u * NBUK + i] = lb[i];
    return;
  }
  int s = b;
  if (s == 0) {
    // ---- conv composite T729 ----
    float* W3  = smem;         // 576
    float* S9s = smem + 576;   // 5184
    float* W1s = smem + 5760;  // 576
    if (tid == 0) rowptr[N] = E;
    for (int e = tid; e < 576; e += 256) { W3[e] = Wc3[e]; W1s[e] = Wc1[e]; }
    __syncthreads();
    for (int bb = tid; bb < 576; bb += 256) {
      float acc[9];
#pragma unroll
      for (int a = 0; a < 9; ++a) acc[a] = 0.0f;
#pragma unroll 4
      for (int o = 0; o < 64; ++o) {
        float w2 = Wc2[o * 576 + bb];
#pragma unroll
        for (int a = 0; a < 9; ++a) acc[a] += W3[o * 9 + a] * w2;
      }
#pragma unroll
      for (int a = 0; a < 9; ++a) S9s[a * 576 + bb] = acc[a];
    }
    __syncthreads();
    for (int c = tid; c < 729; c += 256) {
      int kx0  = c % 3;
      int dl1e = (c / 3) % 3;
      int dl2e = (c / 9) % 3;
      int ky0  = (c / 27) % 3;
      int ky1  = (c / 81) % 3;
      int ky2  = c / 243;
      const float* s9 = &S9s[(ky2 * 3 + dl2e) * 576 + ky1 * 3 + dl1e];
      const float* w1 = &W1s[ky0 * 3 + kx0];
      float t = 0.0f;
#pragma unroll 8
      for (int i = 0; i < 64; ++i) t += s9[i * 9] * w1[i * 9];
      T729[c] = t;
    }
  } else if (s <= 5) {
    // ---- boundary beta vectors ----
    float* S2   = smem;          // 576
    float* W3b  = smem + 576;    // 576
    float* B2   = smem + 1152;   // 64
    float* part = smem + 1216;   // 256
    int var = s - 1;
    for (int e = tid; e < 576; e += 256) {
      int o = e / 9, r = e - o * 9;
      float t = 0.0f;
      for (int i = 0; i < 64; ++i) t += Wc2[o * 576 + i * 9 + r] * bc1[i];
      S2[e] = t;
      W3b[e] = Wc3[e];
    }
    if (tid < 64) B2[tid] = bc2[tid];
    __syncthreads();
    int u = tid & 63, oc = tid >> 6;
    float acc = 0.0f;
    for (int ky2 = 0; ky2 < 3; ++ky2) {
      int o2 = ky2 - 1;
      bool okA = (var == 0) ? (o2 >= 0) : (var == 4) ? (o2 <= 0) : true;
      if (!okA) continue;
      for (int dl2 = -1; dl2 <= 1; ++dl2) {
        int p = u + dl2; if ((unsigned)p >= 64u) continue;
        float sel[9];
#pragma unroll
        for (int ky1 = 0; ky1 < 3; ++ky1) {
          int o1 = ky1 - 1;
          bool mb = maskB(var, o2, o1);
#pragma unroll
          for (int dl1 = -1; dl1 <= 1; ++dl1) {
            int pq = p + dl1;
            sel[ky1 * 3 + dl1 + 1] = (mb && (unsigned)pq < 64u) ? 1.0f : 0.0f;
          }
        }
#pragma unroll 4
        for (int oo = 0; oo < 16; ++oo) {
          int o = oc * 16 + oo;
          float inner = B2[o];
#pragma unroll
          for (int r = 0; r < 9; ++r) inner += S2[o * 9 + r] * sel[r];
          acc += W3b[o * 9 + ky2 * 3 + (dl2 + 1)] * inner;
        }
      }
    }
    part[tid] = acc;
    __syncthreads();
    if (tid < 64) {
      beta5[var * 64 + tid] =
          bc3[0] + part[tid] + part[64 + tid] + part[128 + tid] + part[192 + tid];
    }
  } else {
    // ---- transposes + S-matrices + c5 ----
    int idx = (s - 6) * 256 + tid;  // 0..37119
    if (idx < 16384) {
      int w = idx >> 7, u = idx & 127;
      Wt1[idx] = (u < 64) ? Wl1[u * 128 + w] : Wr1[(u - 64) * 128 + w];
    } else if (idx < 24576) {
      int t = idx - 16384;
      int w = t >> 7, u = t & 127;
      Wt2[t] = (u < 64) ? Wl2[u * 64 + w] : Wr2[(u - 64) * 64 + w];
    } else if (idx < 36864) {
      // S2 = P·P, S1 = Q·P + P·Q, S0 = Q·Q  with P=Wl2^T, Q=Wr2^T.
      int t2 = idx - 24576;
      int m = t2 >> 12, e = t2 & 4095;
      int i = e >> 6, j = e & 63;
      float acc = 0.0f;
#pragma unroll 4
      for (int k = 0; k < 64; ++k) {
        float wlj = Wl2[j * 64 + k], wrj = Wr2[j * 64 + k];
        float wli = Wl2[k * 64 + i], wri = Wr2[k * 64 + i];
        if (m == 0) acc += wli * wlj;
        else if (m == 1) acc += wri * wlj + wli * wrj;
        else acc += wri * wrj;
      }
      Sbuf[t2] = acc;
    } else if (idx < 36928) {
      // c5 = bl2^T (P + Q + I)
      int j = idx - 36864;
      float acc = bl2[j];
      for (int i = 0; i < 64; ++i)
        acc += bl2[i] * (Wl2[j * 64 + i] + Wr2[j * 64 + i]);
      c5[j] = acc;
    }
  }
}

// ============================ PHASE A2 =======================================
// blocks [0,157): edge partition. Bucket base + within-bucket offset both
//   derived from bhist (deterministic, no bcur atomics).
// blocks [157,219): M5T | [219,252): G-matrices | [252,1502): sage1 GEMM
__global__ __launch_bounds__(256) void k_phaseA2(
    const float* __restrict__ X, const float* __restrict__ Wt1,
    float* __restrict__ yzA,
    const int* __restrict__ ei, const int* __restrict__ bhist,
    unsigned long long* __restrict__ ebuf,
    const float* __restrict__ T729, float* __restrict__ M5T,
    const float* __restrict__ Sbuf, const float* __restrict__ c5,
    const float* __restrict__ Wl3, const float* __restrict__ Wr3,
    const float* __restrict__ bl3, float* __restrict__ Gbuf,
    float* __restrict__ c32, int E, int N) {
  __shared__ float smem[2048];  // max branch: gemm Xs (16x128)
  int b = blockIdx.x, tid = threadIdx.x;
  if (b < 157) {
    // ---- partition: bases from bhist column sums ----
    int* lcnt  = (int*)smem;          // 79 (intra-block edge ranks)
    int* lbase = (int*)smem + 128;    // 79 (global write base per bucket)
    int* sscan = (int*)smem + 256;    // 128
    int st = probe_stride(ei);
    for (int i = tid; i < NBUK; i += 256) lcnt[i] = 0;
    int tot = 0, myoff = 0;
    if (tid < NBUK) {
      for (int v = 0; v < 157; ++v) {
        int h = bhist[v * NBUK + tid];
        tot += h;
        if (v < b) myoff += h;
      }
    }
    if (tid < 128) sscan[tid] = (tid < NBUK) ? tot : 0;
    __syncthreads();
    for (int off = 1; off < 128; off <<= 1) {
      int v = 0;
      if (tid < 128 && tid >= off) v = sscan[tid - off];
      __syncthreads();
      if (tid < 128) sscan[tid] += v;
      __syncthreads();
    }
    // sscan inclusive; exclusive = sscan - tot. Block's base = excl + myoff.
    if (tid < NBUK) lbase[tid] = (sscan[tid] - tot) + myoff;
    __syncthreads();
    int e0 = b * 4096;
    int srcv[16], dstv[16], lrank[16], bk[16];
    int n = 0;
#pragma unroll
    for (int t = 0; t < 16; ++t) {
      int e = e0 + t * 256 + tid;
      if (e < E) {
        int sv = ei[(size_t)e * st];
        int d = ei[(size_t)(E + e) * st];
        int bb = d >> 8;
        srcv[n] = sv; dstv[n] = d; bk[n] = bb;
        lrank[n] = atomicAdd(&lcnt[bb], 1);
        ++n;
      }
    }
    for (int t = 0; t < n; ++t) {
      int pos = lbase[bk[t]] + lrank[t];
      ebuf[pos] = ((unsigned long long)(unsigned)dstv[t] << 32) | (unsigned)srcv[t];
    }
  } else if (b < 219) {
    // ---- M5T ----
    float* Ts = smem;  // 729
    for (int e = tid; e < 729; e += 256) Ts[e] = T729[e];
    __syncthreads();
    int idx = (b - 157) * 256 + tid;
    if (idx >= 15680) return;
    int jw = idx % 7;
    int u  = (idx / 7) % 64;
    int d  = (idx / 448) % 7;
    int var = idx / 3136;
    int w = u + jw - 3;
    float acc = 0.0f;
    if (w >= 0 && w < 64) {
      for (int ky2 = 0; ky2 < 3; ++ky2) {
        int o2 = ky2 - 1;
        for (int ky1 = 0; ky1 < 3; ++ky1) {
          int o1 = ky1 - 1;
          if (!maskB(var, o2, o1)) continue;
          int o0 = (d - 3) - o2 - o1;
          if (o0 < -1 || o0 > 1) continue;
          int ky0 = o0 + 1;
          int cbase = ((ky2 * 3 + ky1) * 3 + ky0) * 27;
#pragma unroll
          for (int kx0 = 0; kx0 < 3; ++kx0) {
            int jq = jw - kx0;
            if ((unsigned)jq >= 5u) continue;
            int q = u + jq - 2;
            if ((unsigned)q >= 64u) continue;
#pragma unroll
            for (int dl2e = 0; dl2e < 3; ++dl2e) {
              int p = u + dl2e - 1;
              if ((unsigned)p >= 64u) continue;
              int dl1e = jq - dl2e;
              if ((unsigned)dl1e >= 3u) continue;
              acc += Ts[cbase + dl2e * 9 + dl1e * 3 + kx0];
            }
          }
        }
      }
    }
    if (d == 3 && jw == 3) acc += 1.0f;  // residual: out = conv(h) + h
    M5T[(var * 49 + d * 7 + jw) * 64 + u] = acc;
  } else if (b < 252) {
    // ---- G-matrices: G3=S2·P3, G2=S1·P3+S2·Q3, G1=S0·P3+S1·Q3, G0=S0·Q3 ----
    int bb = b - 219;
    if (bb < 32) {
      int idx = bb * 256 + tid;  // [kblk][t][j]
      int kblk = idx >> 11;
      int rem = idx & 2047;
      int t = rem >> 5, j = rem & 31;
      const float* S2p = Sbuf;
      const float* S1p = Sbuf + 4096;
      const float* S0p = Sbuf + 8192;
      const float* pa = (kblk == 0) ? S2p : (kblk == 1) ? S1p : (kblk == 2) ? S0p : nullptr;
      const float* pb = (kblk == 1) ? S2p : (kblk == 2) ? S1p : (kblk == 3) ? S0p : nullptr;
      float acc = 0.0f;
#pragma unroll 4
      for (int k = 0; k < 64; ++k) {
        if (pa) acc += pa[t * 64 + k] * Wl3[j * 64 + k];
        if (pb) acc += pb[t * 64 + k] * Wr3[j * 64 + k];
      }
      Gbuf[idx] = acc;
    } else if (tid < 32) {
      // c32 = c5^T (P3 + Q3) + bl3^T
      float acc = bl3[tid];
      for (int k = 0; k < 64; ++k)
        acc += c5[k] * (Wl3[tid * 64 + k] + Wr3[tid * 64 + k]);
      c32[tid] = acc;
    }
  } else {
    // ---- sage1 GEMM: yzA = x · Wt1  (C=128, K=128) ----
    constexpr int C = 128, K = 128, ROWS = 16, RPT = ROWS * C / 256;
    float* Xs = smem;
    int y0 = (b - 252) * ROWS;
    {
      const float4* src = (const float4*)(X + (size_t)y0 * K);
      float4* dst = (float4*)Xs;
#pragma unroll
      for (int v = 0; v < ROWS * K / 4 / 256; ++v)
        dst[v * 256 + tid] = src[v * 256 + tid];
    }
    __syncthreads();
    int u = tid % C;
    int rg = tid / C;
    float acc[RPT];
#pragma unroll
    for (int k = 0; k < RPT; ++k) acc[k] = 0.0f;
#pragma unroll 2
    for (int w0 = 0; w0 < K; w0 += 4) {
      float m0 = Wt1[(w0 + 0) * C + u];
      float m1 = Wt1[(w0 + 1) * C + u];
      float m2 = Wt1[(w0 + 2) * C + u];
      float m3 = Wt1[(w0 + 3) * C + u];
      const float* xs = &Xs[(rg * RPT) * K + w0];
#pragma unroll
      for (int k = 0; k < RPT; ++k) {
        float4 h = *(const float4*)(xs + k * K);
        acc[k] += m0 * h.x + m1 * h.y + m2 * h.z + m3 * h.w;
      }
    }
#pragma unroll
    for (int k = 0; k < RPT; ++k)
      yzA[(size_t)(y0 + rg * RPT + k) * C + u] = acc[k];
  }
}

// ============================ PHASE A3 =======================================
// blocks [0,79): per-bucket counting sort (bases/totals from bhist)
// blocks [79,112): Wg = W2^T·[G3|G2|G1|G0], bg = b2^T·[...]
__global__ __launch_bounds__(256) void k_phaseA3(
    const unsigned long long* __restrict__ ebuf, const int* __restrict__ bhist,
    int* __restrict__ rowptr, float* __restrict__ invdeg,
    int* __restrict__ csr,
    const float* __restrict__ Gbuf, const float* __restrict__ W2,
    const float* __restrict__ b2, float* __restrict__ Wg,
    float* __restrict__ bg, int N) {
  __shared__ int smem[772];  // lcnt 256 | lcur 256 | wsum 4 | sscan 128 | tots 128
  int b = blockIdx.x, tid = threadIdx.x;
  if (b < NBUK) {
    int* lcnt  = smem;
    int* lcur  = smem + 256;
    int* wsum  = smem + 512;
    int* sscan = smem + 516;
    int* tots  = smem + 644;
    int tot = 0;
    if (tid < NBUK)
      for (int v = 0; v < 157; ++v) tot += bhist[v * NBUK + tid];
    if (tid < 128) {
      int tv = (tid < NBUK) ? tot : 0;
      tots[tid] = tv;
      sscan[tid] = tv;
    }
    __syncthreads();
    for (int off = 1; off < 128; off <<= 1) {
      int v = 0;
      if (tid < 128 && tid >= off) v = sscan[tid - off];
      __syncthreads();
      if (tid < 128) sscan[tid] += v;
      __syncthreads();
    }
    if (tid < 128) sscan[tid] -= tots[tid];  // exclusive prefix
    __syncthreads();
    int base = sscan[b];
    int n = tots[b];
    lcnt[tid] = 0;
    __syncthreads();
    for (int e = tid; e < n; e += 256) {
      int d = (int)(ebuf[base + e] >> 32);
      atomicAdd(&lcnt[d - (b << 8)], 1);
    }
    __syncthreads();
    int c = lcnt[tid];
    int lane = tid & 63, wid = tid >> 6;
    int s = c;
#pragma unroll
    for (int off = 1; off < 64; off <<= 1) {
      int v = __shfl_up(s, off, 64);
      if (lane >= off) s += v;
    }
    if (lane == 63) wsum[wid] = s;
    __syncthreads();
    int woff = 0;
    for (int w = 0; w < wid; ++w) woff += wsum[w];
    int pref = woff + s - c;  // exclusive
    int gnode = (b << 8) + tid;
    if (gnode < N) {
      rowptr[gnode] = base + pref;
      invdeg[gnode] = 1.0f / (float)(c < 1 ? 1 : c);
    }
    lcur[tid] = pref;
    __syncthreads();
    for (int e = tid; e < n; e += 256) {
      unsigned long long pk = ebuf[base + e];
      int d = (int)(pk >> 32);
      int pos = atomicAdd(&lcur[d - (b << 8)], 1);
      csr[base + pos] = (int)(unsigned)pk;
    }
  } else {
    int bb = b - NBUK;
    if (bb < 32) {
      int idx = bb * 256 + tid;  // Wg[w*128+u]
      int w = idx >> 7, u = idx & 127;
      int kblk = u >> 5, j = u & 31;
      const float* gp = Gbuf + kblk * 2048 + j;
      float acc = 0.0f;
#pragma unroll 4
      for (int t = 0; t < 64; ++t) acc += W2[t * 64 + w] * gp[t * 32];
      Wg[idx] = acc;
    } else if (tid < 128) {
      int kblk = tid >> 5, j = tid & 31;
      const float* gp = Gbuf + kblk * 2048 + j;
      float acc = 0.0f;
      for (int t = 0; t < 64; ++t) acc += b2[t] * gp[t * 32];
      bg[tid] = acc;
    }
  }
}

// ------------------- fused mean-aggregation + GEMM --------------------------
template <int C>
__global__ __launch_bounds__(256) void k_fused(const float* __restrict__ yzin,
                                               const int* __restrict__ csr,
                                               const int* __restrict__ rowptr,
                                               const float* __restrict__ invdeg,
                                               const float* __restrict__ bl,
                                               const float* __restrict__ Wt,
                                               float* __restrict__ out, int N) {
  constexpr int FV = 16;
  constexpr int G  = 4;
  constexpr int S4 = 32;
  constexpr int CAP = 64;
  __shared__ int idxs[16 * CAP];
  __shared__ float htile[16 * 64];
  int tid = threadIdx.x;
  int w = tid >> 6, lane = tid & 63;
  int base = blockIdx.x * 16;
  int beg_r[4], m_r[4], end_r[4];
#pragma unroll
  for (int rr = 0; rr < 4; ++rr) {
    int node = base + w * 4 + rr;
    int beg = rowptr[node], end = rowptr[node + 1];
    beg_r[rr] = beg; end_r[rr] = end;
    int cnt = end - beg;
    int m = cnt < CAP ? cnt : CAP;
    m_r[rr] = m;
    int* my = &idxs[(w * 4 + rr) * CAP];
    for (int k = lane; k < m; k += 64) my[k] = csr[beg + k];
  }
  __syncthreads();
  int g = lane / FV, f = lane % FV;
  const float4* yz4 = (const float4*)yzin;
#pragma unroll
  for (int rr = 0; rr < 4; ++rr) {
    int node = base + w * 4 + rr;
    const int* my = &idxs[(w * 4 + rr) * CAP];
    int m = m_r[rr];
    float a0x=0,a0y=0,a0z=0,a0w=0, a1x=0,a1y=0,a1z=0,a1w=0;
    float a2x=0,a2y=0,a2z=0,a2w=0, a3x=0,a3y=0,a3z=0,a3w=0;
    int j = g;
    for (; j + 3 * G < m; j += 4 * G) {
      int s0 = my[j], s1 = my[j + G], s2 = my[j + 2 * G], s3 = my[j + 3 * G];
      float4 v0 = yz4[(size_t)s0 * S4 + f];
      float4 v1 = yz4[(size_t)s1 * S4 + f];
      float4 v2 = yz4[(size_t)s2 * S4 + f];
      float4 v3 = yz4[(size_t)s3 * S4 + f];
      a0x += v0.x; a0y += v0.y; a0z += v0.z; a0w += v0.w;
      a1x += v1.x; a1y += v1.y; a1z += v1.z; a1w += v1.w;
      a2x += v2.x; a2y += v2.y; a2z += v2.z; a2w += v2.w;
      a3x += v3.x; a3y += v3.y; a3z += v3.z; a3w += v3.w;
    }
    for (; j < m; j += G) {
      int s0 = my[j];
      float4 v0 = yz4[(size_t)s0 * S4 + f];
      a0x += v0.x; a0y += v0.y; a0z += v0.z; a0w += v0.w;
    }
    for (int jj = beg_r[rr] + CAP + g; jj < end_r[rr]; jj += G) {
      int s0 = csr[jj];
      float4 v0 = yz4[(size_t)s0 * S4 + f];
      a0x += v0.x; a0y += v0.y; a0z += v0.z; a0w += v0.w;
    }
    float ax = (a0x + a1x) + (a2x + a3x);
    float ay = (a0y + a1y) + (a2y + a3y);
    float az = (a0z + a1z) + (a2z + a3z);
    float aw = (a0w + a1w) + (a2w + a3w);
#pragma unroll
    for (int mm = FV; mm < 64; mm <<= 1) {
      ax += __shfl_xor(ax, mm, 64);
      ay += __shfl_xor(ay, mm, 64);
      az += __shfl_xor(az, mm, 64);
      aw += __shfl_xor(aw, mm, 64);
    }
    if (g == 0) {
      float4 root = yz4[(size_t)node * S4 + FV + f];
      float4 bv = ((const float4*)bl)[f];
      float id = invdeg[node];
      float4 o;
      o.x = ax * id + bv.x + root.x;
      o.y = ay * id + bv.y + root.y;
      o.z = az * id + bv.z + root.z;
      o.w = aw * id + bv.w + root.w;
      ((float4*)htile)[(w * 4 + rr) * 16 + f] = o;
    }
  }
  __syncthreads();
  constexpr int RPT = 16 * C / 256;
  int u = tid % C, rg = tid / C;
  float acc[RPT];
#pragma unroll
  for (int k = 0; k < RPT; ++k) acc[k] = 0.0f;
#pragma unroll 2
  for (int w0 = 0; w0 < 64; w0 += 4) {
    float m0 = Wt[(w0 + 0) * C + u];
    float m1 = Wt[(w0 + 1) * C + u];
    float m2 = Wt[(w0 + 2) * C + u];
    float m3 = Wt[(w0 + 3) * C + u];
    const float* xs = &htile[(rg * RPT) * 64 + w0];
#pragma unroll
    for (int k = 0; k < RPT; ++k) {
      float4 h4 = *(const float4*)(xs + k * 64);
      acc[k] += m0 * h4.x + m1 * h4.y + m2 * h4.z + m3 * h4.w;
    }
  }
#pragma unroll
  for (int k = 0; k < RPT; ++k)
    out[(size_t)(base + rg * RPT + k) * C + u] = acc[k];
}

// ---------- fused conv-composite apply + (linear2 ∘ sage4-6 collapse) -------
// Output: wbuf[k][node][32], k=0..3 -> w3,w2,w1,w0 for the agg32 chain.
__global__ __launch_bounds__(256) void k_applyfused(
    const float* __restrict__ h, const float* __restrict__ M5T,
    const float* __restrict__ beta5, const float* __restrict__ Wg,
    const float* __restrict__ bg, float* __restrict__ wout, int N) {
  __shared__ float hs[22 * 70];
  __shared__ float htile[16 * 64];
  int tid = threadIdx.x;
  int bstart = blockIdx.x * 16;
  for (int idx = tid; idx < 22 * 70; idx += 256) {
    int row = idx / 70, col = idx - row * 70;
    int y = bstart - 3 + row;
    int ww = col - 3;
    float v = 0.0f;
    if ((unsigned)y < (unsigned)N && (unsigned)ww < 64u)
      v = h[(size_t)y * 64 + ww];
    hs[idx] = v;
  }
  __syncthreads();
  int u = tid & 63, g = tid >> 6;
  int lr0 = g * 4;
  int gstart = bstart + lr0;
  const float* basep = &hs[lr0 * 70 + u];
  bool interior = (gstart >= 2) && (gstart + 3 <= N - 3);
  if (interior) {
    float c[49];
#pragma unroll
    for (int t = 0; t < 49; ++t) c[t] = M5T[(2 * 49 + t) * 64 + u];
    float bet = beta5[2 * 64 + u];
    float acc[4];
#pragma unroll
    for (int k = 0; k < 4; ++k) acc[k] = bet;
#pragma unroll
    for (int rr = 0; rr < 10; ++rr) {
      float t7[7];
#pragma unroll
      for (int jw = 0; jw < 7; ++jw) t7[jw] = basep[rr * 70 + jw];
#pragma unroll
      for (int d = 0; d < 7; ++d) {
        int k = rr - d;
        if (k >= 0 && k < 4) {
#pragma unroll
          for (int jw = 0; jw < 7; ++jw) acc[k] += c[d * 7 + jw] * t7[jw];
        }
      }
    }
#pragma unroll
    for (int k = 0; k < 4; ++k) htile[(lr0 + k) * 64 + u] = acc[k];
  } else {
    for (int k = 0; k < 4; ++k) {
      int y = gstart + k;
      int var = (y == 0) ? 0 : (y == 1) ? 1 : (y == N - 2) ? 3 : (y == N - 1) ? 4 : 2;
      float acc = beta5[var * 64 + u];
      for (int d = 0; d < 7; ++d)
        for (int jw = 0; jw < 7; ++jw)
          acc += M5T[(var * 49 + d * 7 + jw) * 64 + u] * basep[(k + d) * 70 + jw];
      htile[(lr0 + k) * 64 + u] = acc;
    }
  }
  __syncthreads();
  int u2 = tid % 128, rg = tid / 128;
  float acc2[8];
  float bv = bg[u2];
#pragma unroll
  for (int k = 0; k < 8; ++k) acc2[k] = bv;
#pragma unroll 2
  for (int w0 = 0; w0 < 64; w0 += 4) {
    float m0 = Wg[(w0 + 0) * 128 + u2];
    float m1 = Wg[(w0 + 1) * 128 + u2];
    float m2 = Wg[(w0 + 2) * 128 + u2];
    float m3 = Wg[(w0 + 3) * 128 + u2];
    const float* xs = &htile[(rg * 8) * 64 + w0];
#pragma unroll
    for (int k = 0; k < 8; ++k) {
      float4 h4 = *(const float4*)(xs + k * 64);
      acc2[k] += m0 * h4.x + m1 * h4.y + m2 * h4.z + m3 * h4.w;
    }
  }
  int kb = u2 >> 5, jj = u2 & 31;
#pragma unroll
  for (int k = 0; k < 8; ++k) {
    int node = bstart + rg * 8 + k;
    wout[((size_t)kb * N + node) * 32 + jj] = acc2[k];
  }
}

// ------------------ standalone mean aggregation (agg3) ----------------------
template <int DH>
__global__ __launch_bounds__(256) void k_agg(const float* __restrict__ yz,
                                             const int* __restrict__ csr,
                                             const int* __restrict__ rowptr,
                                             const float* __restrict__ invdeg,
                                             const float* __restrict__ bl,
                                             float* __restrict__ out, int N) {
  constexpr int FV = DH / 4;
  constexpr int G  = 64 / FV;
  constexpr int S4 = DH / 2;
  constexpr int CAP = 256;
  __shared__ int idxs[4 * CAP];
  int wid = threadIdx.x >> 6, lane = threadIdx.x & 63;
  int node = blockIdx.x * 4 + wid;
  int beg = rowptr[node], end = rowptr[node + 1];
  int cnt = end - beg;
  int m = cnt < CAP ? cnt : CAP;
  int* my = &idxs[wid * CAP];
  for (int k = lane; k < m; k += 64) my[k] = csr[beg + k];
  __syncthreads();
  int g = lane / FV, f = lane % FV;
  const float4* yz4 = (const float4*)yz;
  float a0x=0,a0y=0,a0z=0,a0w=0, a1x=0,a1y=0,a1z=0,a1w=0;
  float a2x=0,a2y=0,a2z=0,a2w=0, a3x=0,a3y=0,a3z=0,a3w=0;
  int j = g;
  for (; j + 3 * G < m; j += 4 * G) {
    int s0 = my[j], s1 = my[j + G], s2 = my[j + 2 * G], s3 = my[j + 3 * G];
    float4 v0 = yz4[(size_t)s0 * S4 + f];
    float4 v1 = yz4[(size_t)s1 * S4 + f];
    float4 v2 = yz4[(size_t)s2 * S4 + f];
    float4 v3 = yz4[(size_t)s3 * S4 + f];
    a0x += v0.x; a0y += v0.y; a0z += v0.z; a0w += v0.w;
    a1x += v1.x; a1y += v1.y; a1z += v1.z; a1w += v1.w;
    a2x += v2.x; a2y += v2.y; a2z += v2.z; a2w += v2.w;
    a3x += v3.x; a3y += v3.y; a3z += v3.z; a3w += v3.w;
  }
  for (; j < m; j += G) {
    int s0 = my[j];
    float4 v0 = yz4[(size_t)s0 * S4 + f];
    a0x += v0.x; a0y += v0.y; a0z += v0.z; a0w += v0.w;
  }
  for (int jj = beg + CAP + g; jj < end; jj += G) {
    int s0 = csr[jj];
    float4 v0 = yz4[(size_t)s0 * S4 + f];
    a0x += v0.x; a0y += v0.y; a0z += v0.z; a0w += v0.w;
  }
  float ax = (a0x + a1x) + (a2x + a3x);
  float ay = (a0y + a1y) + (a2y + a3y);
  float az = (a0z + a1z) + (a2z + a3z);
  float aw = (a0w + a1w) + (a2w + a3w);
#pragma unroll
  for (int mm = FV; mm < 64; mm <<= 1) {
    ax += __shfl_xor(ax, mm, 64);
    ay += __shfl_xor(ay, mm, 64);
    az += __shfl_xor(az, mm, 64);
    aw += __shfl_xor(aw, mm, 64);
  }
  if (g == 0) {
    float4 root = yz4[(size_t)node * S4 + FV + f];
    float4 bv = ((const float4*)bl)[f];
    float id = invdeg[node];
    float4 o;
    o.x = ax * id + bv.x + root.x;
    o.y = ay * id + bv.y + root.y;
    o.z = az * id + bv.z + root.z;
    o.w = aw * id + bv.w + root.w;
    ((float4*)out)[(size_t)node * FV + f] = o;
  }
}

// ---- 32-wide mean aggregation + elementwise add: out = (A src)·invdeg + add [+ cvec]
__global__ __launch_bounds__(256) void k_agg32(
    const float* __restrict__ src, const int* __restrict__ csr,
    const int* __restrict__ rowptr, const float* __restrict__ invdeg,
    const float* __restrict__ add, const float* __restrict__ cvec,
    float* __restrict__ out, int N) {
  constexpr int FV = 8;    // float4 per 32-float row
  constexpr int G  = 8;    // neighbor-parallel groups per wave
  constexpr int CAP = 256;
  __shared__ int idxs[4 * CAP];
  int wid = threadIdx.x >> 6, lane = threadIdx.x & 63;
  int node = blockIdx.x * 4 + wid;
  int beg = rowptr[node], end = rowptr[node + 1];
  int cnt = end - beg;
  int m = cnt < CAP ? cnt : CAP;
  int* my = &idxs[wid * CAP];
  for (int k = lane; k < m; k += 64) my[k] = csr[beg + k];
  __syncthreads();
  int g = lane / FV, f = lane % FV;
  const float4* sr4 = (const float4*)src;
  float a0x=0,a0y=0,a0z=0,a0w=0, a1x=0,a1y=0,a1z=0,a1w=0;
  float a2x=0,a2y=0,a2z=0,a2w=0, a3x=0,a3y=0,a3z=0,a3w=0;
  int j = g;
  for (; j + 3 * G < m; j += 4 * G) {
    int s0 = my[j], s1 = my[j + G], s2 = my[j + 2 * G], s3 = my[j + 3 * G];
    float4 v0 = sr4[(size_t)s0 * FV + f];
    float4 v1 = sr4[(size_t)s1 * FV + f];
    float4 v2 = sr4[(size_t)s2 * FV + f];
    float4 v3 = sr4[(size_t)s3 * FV + f];
    a0x += v0.x; a0y += v0.y; a0z += v0.z; a0w += v0.w;
    a1x += v1.x; a1y += v1.y; a1z += v1.z; a1w += v1.w;
    a2x += v2.x; a2y += v2.y; a2z += v2.z; a2w += v2.w;
    a3x += v3.x; a3y += v3.y; a3z += v3.z; a3w += v3.w;
  }
  for (; j < m; j += G) {
    int s0 = my[j];
    float4 v0 = sr4[(size_t)s0 * FV + f];
    a0x += v0.x; a0y += v0.y; a0z += v0.z; a0w += v0.w;
  }
  for (int jj = beg + CAP + g; jj < end; jj += G) {
    int s0 = csr[jj];
    float4 v0 = sr4[(size_t)s0 * FV + f];
    a0x += v0.x; a0y += v0.y; a0z += v0.z; a0w += v0.w;
  }
  float ax = (a0x + a1x) + (a2x + a3x);
  float ay = (a0y + a1y) + (a2y + a3y);
  float az = (a0z + a1z) + (a2z + a3z);
  float aw = (a0w + a1w) + (a2w + a3w);
#pragma unroll
  for (int mm = FV; mm < 64; mm <<= 1) {
    ax += __shfl_xor(ax, mm, 64);
    ay += __shfl_xor(ay, mm, 64);
    az += __shfl_xor(az, mm, 64);
    aw += __shfl_xor(aw, mm, 64);
  }
  if (g == 0) {
    float4 av = ((const float4*)add)[(size_t)node * FV + f];
    float id = invdeg[node];
    float4 o;
    o.x = ax * id + av.x;
    o.y = ay * id + av.y;
    o.z = az * id + av.z;
    o.w = aw * id + av.w;
    if (cvec != nullptr) {
      float4 cv = ((const float4*)cvec)[f];
      o.x += cv.x; o.y += cv.y; o.z += cv.z; o.w += cv.w;
    }
    ((float4*)out)[(size_t)node * FV + f] = o;
  }
}

// ------------------------------- launcher -----------------------------------
extern "C" void kernel_launch(void* const* d_in, const int* in_sizes, int n_in,
                              void* d_out, int out_size, void* d_ws, size_t ws_size,
                              hipStream_t stream) {
  const int N = NN, E = NE;
  const float* x   = (const float*)d_in[0];
  const int*   ei  = (const int*)d_in[1];
  const float* Wl1 = (const float*)d_in[2];
  const float* bl1 = (const float*)d_in[3];
  const float* Wr1 = (const float*)d_in[4];
  const float* Wl2 = (const float*)d_in[5];
  const float* bl2 = (const float*)d_in[6];
  const float* Wr2 = (const float*)d_in[7];
  const float* Wl3 = (const float*)d_in[8];
  const float* bl3 = (const float*)d_in[9];
  const float* Wr3 = (const float*)d_in[10];
  const float* Wc1 = (const float*)d_in[11];
  const float* bc1 = (const float*)d_in[12];
  const float* Wc2 = (const float*)d_in[13];
  const float* bc2 = (const float*)d_in[14];
  const float* Wc3 = (const float*)d_in[15];
  const float* bc3 = (const float*)d_in[16];
  const float* W2  = (const float*)d_in[17];
  const float* b2  = (const float*)d_in[18];

  char* ws = (char*)d_ws;
  size_t off = 0;
  auto alloc = [&](size_t bytes) -> void* {
    off = (off + 255) & ~(size_t)255;
    void* p = ws + off;
    off += bytes;
    return p;
  };
  int*   rowptr  = (int*)alloc((size_t)(N + 1) * 4);
  float* invdeg  = (float*)alloc((size_t)N * 4);
  int*   csr     = (int*)alloc((size_t)E * 4);
  unsigned long long* ebuf = (unsigned long long*)alloc((size_t)E * 8);
  int*   bhist   = (int*)alloc(157 * NBUK * 4);  // per-block hist rows (no init)
  float* Wt1     = (float*)alloc(128 * 128 * 4);
  float* Wt2     = (float*)alloc(64 * 128 * 4);
  float* T729    = (float*)alloc(729 * 4);
  float* M5T     = (float*)alloc(15680 * 4);
  float* beta5   = (float*)alloc(320 * 4);
  float* Sbuf    = (float*)alloc(12288 * 4);
  float* c5      = (float*)alloc(64 * 4);
  float* Gbuf    = (float*)alloc(8192 * 4);
  float* Wg      = (float*)alloc(8192 * 4);
  float* bg      = (float*)alloc(128 * 4);
  float* c32     = (float*)alloc(32 * 4);
  float* yzA     = (float*)alloc((size_t)N * 128 * 4);
  float* yzB     = (float*)alloc((size_t)N * 128 * 4);
  float* hA      = (float*)alloc((size_t)N * 64 * 4);
  float* wbuf    = (float*)alloc((size_t)4 * N * 32 * 4);
  float* s1buf   = (float*)alloc((size_t)N * 32 * 4);
  float* s2buf   = (float*)alloc((size_t)N * 32 * 4);
  (void)ws_size; (void)in_sizes; (void)n_in; (void)out_size;

  const int gG = N / 16;  // 1250
  const int gA = N / 4;   // 5000

  // A1: setup(151) || hist(157)  [no memset needed: bhist rows fully written]
  k_phaseA1<<<308, 256, 0, stream>>>(ei, bhist, Wc1, Wc2, Wc3, bc1, bc2, bc3,
                                     Wl1, Wr1, Wl2, Wr2, bl2,
                                     T729, beta5, Wt1, Wt2, Sbuf, c5,
                                     rowptr, E, N);
  // A2: part(157) || m5(62) || setupG(33) || sage1-GEMM(1250)
  k_phaseA2<<<1502, 256, 0, stream>>>(x, Wt1, yzA, ei, bhist, ebuf,
                                      T729, M5T, Sbuf, c5, Wl3, Wr3, bl3,
                                      Gbuf, c32, E, N);
  // A3: sortb(79) || setupWg(33)
  k_phaseA3<<<112, 256, 0, stream>>>(ebuf, bhist, rowptr, invdeg, csr,
                                     Gbuf, W2, b2, Wg, bg, N);

  // [agg1 + sage2-transform]
  k_fused<128><<<gG, 256, 0, stream>>>(yzA, csr, rowptr, invdeg, bl1, Wt2, yzB, N);
  // [agg2 + sage3-transform]
  k_fused<128><<<gG, 256, 0, stream>>>(yzB, csr, rowptr, invdeg, bl2, Wt2, yzA, N);
  // agg3 -> hA (conv input)
  k_agg<64><<<gA, 256, 0, stream>>>(yzA, csr, rowptr, invdeg, bl2, hA, N);
  // [conv-composite + residual + linear2 + sage4-6 weight collapse] -> w3|w2|w1|w0
  k_applyfused<<<gG, 256, 0, stream>>>(hA, M5T, beta5, Wg, bg, wbuf, N);
  // collapsed sage4-6: out = A(A(A w3 + w2) + w1) + w0 + c32
  const float* w3  = wbuf;
  const float* w2p = wbuf + (size_t)N * 32;
  const float* w1p = wbuf + (size_t)2 * N * 32;
  const float* w0p = wbuf + (size_t)3 * N * 32;
  k_agg32<<<gA, 256, 0, stream>>>(w3, csr, rowptr, invdeg, w2p, nullptr, s1buf, N);
  k_agg32<<<gA, 256, 0, stream>>>(s1buf, csr, rowptr, invdeg, w1p, nullptr, s2buf, N);
  k_agg32<<<gA, 256, 0, stream>>>(s2buf, csr, rowptr, invdeg, w0p, c32, (float*)d_out, N);
}